// Round 1
// baseline (629.315 us; speedup 1.0000x reference)
//
#include <hip/hip_runtime.h>
#include <hip/hip_bf16.h>
#include <stdint.h>

#define BM 64
#define BN 64
#define BK 32
#define GEMM_THREADS 256

typedef float f32x4 __attribute__((ext_vector_type(4)));
typedef short bf16x8 __attribute__((ext_vector_type(8)));

static __device__ __forceinline__ ushort f2bf(float f) {
    union { __hip_bfloat16 h; ushort u; } cv;
    cv.h = __float2bfloat16(f);
    return cv.u;
}
static __device__ __forceinline__ float bf2f(ushort u) {
    union { ushort u; __hip_bfloat16 h; } cv;
    cv.u = u;
    return __bfloat162float(cv.h);
}

static __device__ __forceinline__ void gload_lds16(const void* g, void* l) {
    __builtin_amdgcn_global_load_lds(
        (const __attribute__((address_space(1))) unsigned int*)g,
        (__attribute__((address_space(3))) unsigned int*)l,
        16, 0, 0);
}

// C = A @ B^T (+ epilogue). A: MxK bf16 row-major, B: NxK bf16 row-major.
// MODE 0: outf[r*N+c]  = acc + biasp[c]                  (bias init, biasp = b[N])
// MODE 1: outf[r*N+c] += acc                             (bias accumulate pass)
// MODE 2: outz[r*N+c]  = bf16(relu(acc + biasp[r*N+c]))  (fixed-point iteration)
// MODE 3: outf[r*N+c]  = relu(acc + biasp[r*N+c])        (final output, f32)
template<int MODE>
__global__ __launch_bounds__(GEMM_THREADS, 2)
void gemm_bt(const ushort* __restrict__ A, const ushort* __restrict__ B,
             const float* __restrict__ biasp, float* __restrict__ outf,
             ushort* __restrict__ outz, int M, int N, int K)
{
    __shared__ ushort lds[2][(BM + BN) * BK];   // A tile [64][32] then B tile [64][32]
    const int tid  = threadIdx.x;
    const int lane = tid & 63;
    const int wave = tid >> 6;
    const int row0 = blockIdx.x * BM;
    const int col0 = blockIdx.y * BN;
    const int wr = (wave >> 1) * 32;   // wave sub-tile row
    const int wc = (wave & 1) * 32;    // wave sub-tile col

    // staging: 512 chunks of 16B per k-step (A:256, B:256); chunk id = tid
    const int srow = tid >> 2;         // 0..63
    const int skc  = (tid & 3) * 8;    // bf16 element offset in k
    const ushort* asrc = A + (size_t)(row0 + srow) * K + skc;
    const ushort* bsrc = B + (size_t)(col0 + srow) * K + skc;

    f32x4 acc[2][2] = {};

    const int nk = K / BK;
    int cur = 0;

    // prologue: stage kt=0 into buffer 0 (LDS dest wave-uniform base + lane*16B)
    gload_lds16(asrc, &lds[0][wave * 512]);
    gload_lds16(bsrc, &lds[0][2048 + wave * 512]);
    __syncthreads();

    for (int kt = 0; kt < nk; ++kt) {
        if (kt + 1 < nk) {
            const ushort* a2 = asrc + (size_t)(kt + 1) * BK;
            const ushort* b2 = bsrc + (size_t)(kt + 1) * BK;
            gload_lds16(a2, &lds[cur ^ 1][wave * 512]);
            gload_lds16(b2, &lds[cur ^ 1][2048 + wave * 512]);
        }
        const ushort* base = lds[cur];
        const int ko = (lane >> 4) * 8;
        const int rA = lane & 15;
        bf16x8 a0 = *(const bf16x8*)&base[(wr + rA) * BK + ko];
        bf16x8 a1 = *(const bf16x8*)&base[(wr + 16 + rA) * BK + ko];
        bf16x8 b0 = *(const bf16x8*)&base[2048 + (wc + rA) * BK + ko];
        bf16x8 b1 = *(const bf16x8*)&base[2048 + (wc + 16 + rA) * BK + ko];
        acc[0][0] = __builtin_amdgcn_mfma_f32_16x16x32_bf16(a0, b0, acc[0][0], 0, 0, 0);
        acc[0][1] = __builtin_amdgcn_mfma_f32_16x16x32_bf16(a0, b1, acc[0][1], 0, 0, 0);
        acc[1][0] = __builtin_amdgcn_mfma_f32_16x16x32_bf16(a1, b0, acc[1][0], 0, 0, 0);
        acc[1][1] = __builtin_amdgcn_mfma_f32_16x16x32_bf16(a1, b1, acc[1][1], 0, 0, 0);
        __syncthreads();
        cur ^= 1;
    }

    // C/D layout (m89-verified): col = lane&15, row = (lane>>4)*4 + j
    const int rb = row0 + wr + ((lane >> 4) << 2);
    const int cb = col0 + wc + (lane & 15);
    #pragma unroll
    for (int mf = 0; mf < 2; ++mf)
    #pragma unroll
    for (int nf = 0; nf < 2; ++nf)
    #pragma unroll
    for (int j = 0; j < 4; ++j) {
        const int r = rb + mf * 16 + j;
        const int c = cb + nf * 16;
        const size_t idx = (size_t)r * N + c;
        const float v = acc[mf][nf][j];
        if constexpr (MODE == 0) {
            outf[idx] = v + biasp[c];
        } else if constexpr (MODE == 1) {
            outf[idx] += v;
        } else if constexpr (MODE == 2) {
            float t = v + biasp[idx];
            outz[idx] = f2bf(t > 0.f ? t : 0.f);
        } else {
            float t = v + biasp[idx];
            outf[idx] = t > 0.f ? t : 0.f;
        }
    }
}

// f32 -> (bf16 hi, bf16 lo residual), vectorized x4
__global__ void k_split(const float* __restrict__ in, ushort* __restrict__ hi,
                        ushort* __restrict__ lo, int n4)
{
    int i = blockIdx.x * blockDim.x + threadIdx.x;
    const int stride = gridDim.x * blockDim.x;
    for (; i < n4; i += stride) {
        f32x4 v = ((const f32x4*)in)[i];
        ushort4 h, l;
        #pragma unroll
        for (int j = 0; j < 4; ++j) {
            float f = v[j];
            ushort hb = f2bf(f);
            ((ushort*)&h)[j] = hb;
            ((ushort*)&l)[j] = f2bf(f - bf2f(hb));
        }
        ((ushort4*)hi)[i] = h;
        ((ushort4*)lo)[i] = l;
    }
}

__global__ void k_conv(const float* __restrict__ in, ushort* __restrict__ out, int n4)
{
    int i = blockIdx.x * blockDim.x + threadIdx.x;
    const int stride = gridDim.x * blockDim.x;
    for (; i < n4; i += stride) {
        f32x4 v = ((const f32x4*)in)[i];
        ushort4 h;
        #pragma unroll
        for (int j = 0; j < 4; ++j) ((ushort*)&h)[j] = f2bf(v[j]);
        ((ushort4*)out)[i] = h;
    }
}

__global__ void k_relu_bf16(const float* __restrict__ in, ushort* __restrict__ out, int n4)
{
    int i = blockIdx.x * blockDim.x + threadIdx.x;
    const int stride = gridDim.x * blockDim.x;
    for (; i < n4; i += stride) {
        f32x4 v = ((const f32x4*)in)[i];
        ushort4 h;
        #pragma unroll
        for (int j = 0; j < 4; ++j) {
            float f = v[j] > 0.f ? v[j] : 0.f;
            ((ushort*)&h)[j] = f2bf(f);
        }
        ((ushort4*)out)[i] = h;
    }
}

extern "C" void kernel_launch(void* const* d_in, const int* in_sizes, int n_in,
                              void* d_out, int out_size, void* d_ws, size_t ws_size,
                              hipStream_t stream)
{
    const float* x = (const float*)d_in[0];   // 512 x 3072
    const float* W = (const float*)d_in[1];   // 4096 x 4096
    const float* U = (const float*)d_in[2];   // 4096 x 3072
    const float* b = (const float*)d_in[3];   // 4096
    float* out = (float*)d_out;               // 512 x 4096 f32

    const int Mb = 512, DIN = 3072, D = 4096;
    const int NUM_ITERS = 9;  // Picard: ||W||_2 ~ 0.2 -> 0.2^10 * ||z*|| ~ 1e-4 Frobenius

    char* ws = (char*)d_ws;
    size_t off = 0;
    auto take = [&](size_t bytes) {
        void* p = (void*)(ws + off);
        off += (bytes + 255) & ~(size_t)255;
        return p;
    };
    ushort* Wbf  = (ushort*)take((size_t)D * D * 2);      // 33.6 MB
    ushort* Uh   = (ushort*)take((size_t)D * DIN * 2);    // 25.2 MB
    ushort* Ul   = (ushort*)take((size_t)D * DIN * 2);    // 25.2 MB
    ushort* xh   = (ushort*)take((size_t)Mb * DIN * 2);   //  3.1 MB
    ushort* xl   = (ushort*)take((size_t)Mb * DIN * 2);   //  3.1 MB
    float*  bias = (float*)take((size_t)Mb * D * 4);      //  8.4 MB
    ushort* z0   = (ushort*)take((size_t)Mb * D * 2);     //  4.2 MB
    ushort* z1   = (ushort*)take((size_t)Mb * D * 2);     //  4.2 MB

    const int EB = 256;
    k_conv <<<dim3(2048), dim3(EB), 0, stream>>>(W, Wbf, D * D / 4);
    k_split<<<dim3(2048), dim3(EB), 0, stream>>>(U, Uh, Ul, D * DIN / 4);
    k_split<<<dim3(512),  dim3(EB), 0, stream>>>(x, xh, xl, Mb * DIN / 4);

    dim3 ggrid(Mb / BM, D / BN);
    dim3 gblk(GEMM_THREADS);
    // bias = x @ U^T + b, split-bf16 for ~f32 accuracy (3 MFMA passes)
    gemm_bt<0><<<ggrid, gblk, 0, stream>>>(xh, Uh, b, bias, nullptr, Mb, D, DIN);
    gemm_bt<1><<<ggrid, gblk, 0, stream>>>(xl, Uh, nullptr, bias, nullptr, Mb, D, DIN);
    gemm_bt<1><<<ggrid, gblk, 0, stream>>>(xh, Ul, nullptr, bias, nullptr, Mb, D, DIN);

    // z1 = relu(bias)
    k_relu_bf16<<<dim3(512), dim3(EB), 0, stream>>>(bias, z0, Mb * D / 4);

    // Picard iterations: z <- relu(z @ W^T + bias)
    ushort* zc = z0;
    ushort* zn = z1;
    for (int t = 0; t < NUM_ITERS; ++t) {
        gemm_bt<2><<<ggrid, gblk, 0, stream>>>(zc, Wbf, bias, nullptr, zn, Mb, D, D);
        ushort* tmp = zc; zc = zn; zn = tmp;
    }
    // out = relu(z @ W^T + bias), f32
    gemm_bt<3><<<ggrid, gblk, 0, stream>>>(zc, Wbf, bias, out, nullptr, Mb, D, D);

    (void)in_sizes; (void)n_in; (void)out_size; (void)ws_size;
}

// Round 2
// 256.741 us; speedup vs baseline: 2.4512x; 2.4512x over previous
//
#include <hip/hip_runtime.h>
#include <hip/hip_bf16.h>
#include <stdint.h>

typedef float f32x4 __attribute__((ext_vector_type(4)));
typedef short bf16x8 __attribute__((ext_vector_type(8)));

static __device__ __forceinline__ ushort f2bf(float f) {
    union { __hip_bfloat16 h; ushort u; } cv;
    cv.h = __float2bfloat16(f);
    return cv.u;
}

static __device__ __forceinline__ void gload_lds16(const void* g, void* l) {
    __builtin_amdgcn_global_load_lds(
        (const __attribute__((address_space(1))) unsigned int*)g,
        (__attribute__((address_space(3))) unsigned int*)l,
        16, 0, 0);
}

// C = A @ B^T partials. A: MxK bf16 rm, B: NxK bf16 rm.
// Tile 128x128, BK=64, split-K=2 -> parts[zk][M][N] f32.
// Grid: 1D, (M/128)*(N/128)*2 blocks (must be 256 here: 4 x 32 x 2).
// LDS chunk swizzle: 16B chunk c of row r stored at slot c ^ (r&7)
// (applied by pre-swizzling the global source; LDS dest stays linear).
__global__ __launch_bounds__(256, 1)
void gemm128_sk2(const ushort* __restrict__ A, const ushort* __restrict__ B,
                 float* __restrict__ parts, int M, int N, int K)
{
    __shared__ ushort lds[2][16384];   // [buf][ A:8192 | B:8192 ] elements (64 KiB total)
    const int tid  = threadIdx.x;
    const int lane = tid & 63;
    const int wave = tid >> 6;

    // XCD-aware swizzle: xcd = bid%8 owns 4 consecutive N-tiles (512 cols -> 4MB W slice in its L2)
    const int bid = blockIdx.x;
    const int s   = bid >> 3;
    const int xt  = s & 3;                  // M-tile (4)
    const int yl  = (s >> 2) & 3;
    const int zk  = s >> 4;                 // split-K half (2)
    const int yt  = (bid & 7) * 4 + yl;     // N-tile (32)
    const int row0 = xt * 128;
    const int col0 = yt * 128;
    const int Ksub = K >> 1;
    const int koff = zk * Ksub;

    // staging: A tile = 1024 16B-chunks, 4 calls x (4 waves x 64 lanes)
    size_t aoff[4], boff[4];
    #pragma unroll
    for (int c = 0; c < 4; ++c) {
        const int q   = c * 256 + tid;
        const int row = q >> 3;                      // 0..127
        const int cg  = (q & 7) ^ (row & 7);         // pre-swizzled source chunk
        aoff[c] = (size_t)(row0 + row) * K + koff + cg * 8;
        boff[c] = (size_t)(col0 + row) * K + koff + cg * 8;
    }

    const int wr = (wave >> 1) * 64;
    const int wc = (wave & 1) * 64;
    const int rA = lane & 15;
    const int kq = lane >> 4;
    const int so0 = (kq ^ (rA & 7)) * 8;   // swizzled element offset, kk=0; kk=1 -> ^32

    f32x4 acc[4][4] = {};
    const int nk = Ksub >> 6;
    int cur = 0;

    #pragma unroll
    for (int c = 0; c < 4; ++c) {
        gload_lds16(A + aoff[c], &lds[0][(c * 256 + wave * 64) * 8]);
        gload_lds16(B + boff[c], &lds[0][8192 + (c * 256 + wave * 64) * 8]);
    }
    __syncthreads();

    for (int kt = 0; kt < nk; ++kt) {
        if (kt + 1 < nk) {
            const size_t kadd = (size_t)(kt + 1) * 64;
            #pragma unroll
            for (int c = 0; c < 4; ++c) {
                gload_lds16(A + aoff[c] + kadd, &lds[cur ^ 1][(c * 256 + wave * 64) * 8]);
                gload_lds16(B + boff[c] + kadd, &lds[cur ^ 1][8192 + (c * 256 + wave * 64) * 8]);
            }
        }
        const ushort* base = lds[cur];
        #pragma unroll
        for (int kk = 0; kk < 2; ++kk) {
            const int so = so0 ^ (kk * 32);
            bf16x8 a[4], b[4];
            #pragma unroll
            for (int m = 0; m < 4; ++m)
                a[m] = *(const bf16x8*)&base[(wr + m * 16 + rA) * 64 + so];
            #pragma unroll
            for (int n = 0; n < 4; ++n)
                b[n] = *(const bf16x8*)&base[8192 + (wc + n * 16 + rA) * 64 + so];
            #pragma unroll
            for (int m = 0; m < 4; ++m)
                #pragma unroll
                for (int n = 0; n < 4; ++n)
                    acc[m][n] = __builtin_amdgcn_mfma_f32_16x16x32_bf16(a[m], b[n], acc[m][n], 0, 0, 0);
        }
        __syncthreads();
        cur ^= 1;
    }

    // C/D layout: col = lane&15, row = (lane>>4)*4 + j
    float* po = parts + (size_t)zk * M * N;
    const int rb = row0 + wr + (lane >> 4) * 4;
    const int cb = col0 + wc + (lane & 15);
    #pragma unroll
    for (int m = 0; m < 4; ++m)
        #pragma unroll
        for (int n = 0; n < 4; ++n)
            #pragma unroll
            for (int j = 0; j < 4; ++j)
                po[(size_t)(rb + m * 16 + j) * N + cb + n * 16] = acc[m][n][j];
}

// combine split-K partials + epilogue.
// MODE 0: t = p0+p1+bvec[c];  biasf_out = t; zout = bf16(relu(t))
// MODE 1: t = p0+p1+biasf_in; zout = bf16(relu(t))
// MODE 2: t = p0+p1+biasf_in; fout = relu(t)
template<int MODE>
__global__ void k_combine(const float* __restrict__ p, const float* __restrict__ biasf_in,
                          const float* __restrict__ bvec, float* __restrict__ biasf_out,
                          ushort* __restrict__ zout, float* __restrict__ fout,
                          int n4, int Ndiv4)
{
    const int i = blockIdx.x * blockDim.x + threadIdx.x;
    if (i >= n4) return;
    f32x4 v = ((const f32x4*)p)[i] + ((const f32x4*)p)[i + n4];
    if constexpr (MODE == 0) {
        v += ((const f32x4*)bvec)[i % Ndiv4];
        ((f32x4*)biasf_out)[i] = v;
        ushort4 h;
        #pragma unroll
        for (int j = 0; j < 4; ++j) h[j] = f2bf(v[j] > 0.f ? v[j] : 0.f);
        ((ushort4*)zout)[i] = h;
    } else if constexpr (MODE == 1) {
        v += ((const f32x4*)biasf_in)[i];
        ushort4 h;
        #pragma unroll
        for (int j = 0; j < 4; ++j) h[j] = f2bf(v[j] > 0.f ? v[j] : 0.f);
        ((ushort4*)zout)[i] = h;
    } else {
        v += ((const f32x4*)biasf_in)[i];
        f32x4 r;
        #pragma unroll
        for (int j = 0; j < 4; ++j) r[j] = v[j] > 0.f ? v[j] : 0.f;
        ((f32x4*)fout)[i] = r;
    }
}

// f32 -> bf16 convert, x4 vectorized, grid-stride
__global__ void k_conv(const float* __restrict__ in, ushort* __restrict__ out, int n4)
{
    int i = blockIdx.x * blockDim.x + threadIdx.x;
    const int stride = gridDim.x * blockDim.x;
    for (; i < n4; i += stride) {
        f32x4 v = ((const f32x4*)in)[i];
        ushort4 h;
        #pragma unroll
        for (int j = 0; j < 4; ++j) h[j] = f2bf(v[j]);
        ((ushort4*)out)[i] = h;
    }
}

extern "C" void kernel_launch(void* const* d_in, const int* in_sizes, int n_in,
                              void* d_out, int out_size, void* d_ws, size_t ws_size,
                              hipStream_t stream)
{
    const float* x = (const float*)d_in[0];   // 512 x 3072
    const float* W = (const float*)d_in[1];   // 4096 x 4096
    const float* U = (const float*)d_in[2];   // 4096 x 3072
    const float* b = (const float*)d_in[3];   // 4096
    float* out = (float*)d_out;               // 512 x 4096 f32

    const int Mb = 512, DIN = 3072, D = 4096;
    const int NUM_ITERS = 5;   // 0.2-contraction: truncation << bf16 noise after 5 iters

    char* ws = (char*)d_ws;
    size_t off = 0;
    auto take = [&](size_t bytes) {
        void* p = (void*)(ws + off);
        off += (bytes + 255) & ~(size_t)255;
        return p;
    };
    ushort* Wbf   = (ushort*)take((size_t)D * D * 2);        // 33.6 MB
    ushort* Ubf   = (ushort*)take((size_t)D * DIN * 2);      // 25.2 MB
    ushort* xbf   = (ushort*)take((size_t)Mb * DIN * 2);     //  3.1 MB
    float*  biasf = (float*)take((size_t)Mb * D * 4);        //  8.4 MB
    float*  parts = (float*)take((size_t)2 * Mb * D * 4);    // 16.8 MB
    ushort* z0    = (ushort*)take((size_t)Mb * D * 2);       //  4.2 MB
    ushort* z1    = (ushort*)take((size_t)Mb * D * 2);       //  4.2 MB

    const int EB = 256;
    k_conv<<<dim3(4096), dim3(EB), 0, stream>>>(W, Wbf, D * D / 4);
    k_conv<<<dim3(4096), dim3(EB), 0, stream>>>(U, Ubf, D * DIN / 4);
    k_conv<<<dim3(1536), dim3(EB), 0, stream>>>(x, xbf, Mb * DIN / 4);

    const int n4 = Mb * D / 4;           // 524288
    const dim3 cgrid(n4 / EB);           // 2048
    const dim3 ggrid(256);               // (512/128) * (4096/128) * 2
    const dim3 gblk(256);

    // bias = x @ U^T + b (bf16 single-pass; error ~0.02 absmax, within budget)
    gemm128_sk2<<<ggrid, gblk, 0, stream>>>(xbf, Ubf, parts, Mb, D, DIN);
    k_combine<0><<<cgrid, dim3(EB), 0, stream>>>(parts, nullptr, b, biasf, z0, nullptr, n4, D / 4);

    // Picard: z <- relu(z @ W^T + bias)
    ushort* zc = z0;
    ushort* zn = z1;
    for (int t = 0; t < NUM_ITERS; ++t) {
        gemm128_sk2<<<ggrid, gblk, 0, stream>>>(zc, Wbf, parts, Mb, D, D);
        k_combine<1><<<cgrid, dim3(EB), 0, stream>>>(parts, biasf, nullptr, nullptr, zn, nullptr, n4, D / 4);
        ushort* tmp = zc; zc = zn; zn = tmp;
    }
    // out = relu(z @ W^T + bias), f32
    gemm128_sk2<<<ggrid, gblk, 0, stream>>>(zc, Wbf, parts, Mb, D, D);
    k_combine<2><<<cgrid, dim3(EB), 0, stream>>>(parts, biasf, nullptr, nullptr, nullptr, out, n4, D / 4);

    (void)in_sizes; (void)n_in; (void)out_size; (void)ws_size;
}

// Round 3
// 203.925 us; speedup vs baseline: 3.0860x; 1.2590x over previous
//
#include <hip/hip_runtime.h>
#include <hip/hip_bf16.h>
#include <stdint.h>

typedef float f32x4 __attribute__((ext_vector_type(4)));
typedef short bf16x8 __attribute__((ext_vector_type(8)));

static __device__ __forceinline__ ushort f2bf(float f) {
    union { __hip_bfloat16 h; ushort u; } cv;
    cv.h = __float2bfloat16(f);
    return cv.u;
}

static __device__ __forceinline__ void gload_lds16(const void* g, void* l) {
    __builtin_amdgcn_global_load_lds(
        (const __attribute__((address_space(1))) unsigned int*)g,
        (__attribute__((address_space(3))) unsigned int*)l,
        16, 0, 0);
}

// C = A @ B^T partials. A: MxK bf16 rm, B: NxK bf16 rm.
// Tile 128x128, BK=64, split-K=4 -> parts[zk][M][N] f32.
// Grid: 512 blocks = 4(M) x 32(N) x 4(zk); 2 blocks/CU for barrier-drain overlap.
// LDS chunk swizzle: 16B chunk c of row r stored at slot c ^ (r&7)
// (applied by pre-swizzling the global source; LDS dest stays linear).
__global__ __launch_bounds__(256, 2)
void gemm128_sk4(const ushort* __restrict__ A, const ushort* __restrict__ B,
                 float* __restrict__ parts, int M, int N, int K)
{
    __shared__ ushort lds[2][16384];   // [buf][ A:8192 | B:8192 ] elements (64 KiB)
    const int tid  = threadIdx.x;
    const int lane = tid & 63;
    const int wave = tid >> 6;

    // XCD swizzle: xcd = bid%8 owns 4 consecutive N-tiles (512 cols -> 4MB W slice/L2)
    const int bid = blockIdx.x;
    const int s   = bid >> 3;
    const int xt  = s & 3;                  // M-tile (4)
    const int yl  = (s >> 2) & 3;
    const int zk  = s >> 4;                 // split-K quarter (4)
    const int yt  = (bid & 7) * 4 + yl;     // N-tile (32)
    const int row0 = xt * 128;
    const int col0 = yt * 128;
    const int Ksub = K >> 2;
    const int koff = zk * Ksub;

    // staging: A tile = 1024 16B-chunks, 4 calls x (4 waves x 64 lanes)
    size_t aoff[4], boff[4];
    #pragma unroll
    for (int c = 0; c < 4; ++c) {
        const int q   = c * 256 + tid;
        const int row = q >> 3;                      // 0..127
        const int cg  = (q & 7) ^ (row & 7);         // pre-swizzled source chunk
        aoff[c] = (size_t)(row0 + row) * K + koff + cg * 8;
        boff[c] = (size_t)(col0 + row) * K + koff + cg * 8;
    }

    const int wr = (wave >> 1) * 64;
    const int wc = (wave & 1) * 64;
    const int rA = lane & 15;
    const int kq = lane >> 4;
    const int so0 = (kq ^ (rA & 7)) * 8;   // swizzled element offset, kk=0; kk=1 -> ^32

    f32x4 acc[4][4] = {};
    const int nk = Ksub >> 6;
    int cur = 0;

    #pragma unroll
    for (int c = 0; c < 4; ++c) {
        gload_lds16(A + aoff[c], &lds[0][(c * 256 + wave * 64) * 8]);
        gload_lds16(B + boff[c], &lds[0][8192 + (c * 256 + wave * 64) * 8]);
    }
    __syncthreads();

    for (int kt = 0; kt < nk; ++kt) {
        if (kt + 1 < nk) {
            const size_t kadd = (size_t)(kt + 1) * 64;
            #pragma unroll
            for (int c = 0; c < 4; ++c) {
                gload_lds16(A + aoff[c] + kadd, &lds[cur ^ 1][(c * 256 + wave * 64) * 8]);
                gload_lds16(B + boff[c] + kadd, &lds[cur ^ 1][8192 + (c * 256 + wave * 64) * 8]);
            }
        }
        const ushort* base = lds[cur];
        #pragma unroll
        for (int kk = 0; kk < 2; ++kk) {
            const int so = so0 ^ (kk * 32);
            bf16x8 a[4], b[4];
            #pragma unroll
            for (int m = 0; m < 4; ++m)
                a[m] = *(const bf16x8*)&base[(wr + m * 16 + rA) * 64 + so];
            #pragma unroll
            for (int n = 0; n < 4; ++n)
                b[n] = *(const bf16x8*)&base[8192 + (wc + n * 16 + rA) * 64 + so];
            #pragma unroll
            for (int m = 0; m < 4; ++m)
                #pragma unroll
                for (int n = 0; n < 4; ++n)
                    acc[m][n] = __builtin_amdgcn_mfma_f32_16x16x32_bf16(a[m], b[n], acc[m][n], 0, 0, 0);
        }
        __syncthreads();
        cur ^= 1;
    }

    // C/D layout: col = lane&15, row = (lane>>4)*4 + j
    float* po = parts + (size_t)zk * M * N;
    const int rb = row0 + wr + (lane >> 4) * 4;
    const int cb = col0 + wc + (lane & 15);
    #pragma unroll
    for (int m = 0; m < 4; ++m)
        #pragma unroll
        for (int n = 0; n < 4; ++n)
            #pragma unroll
            for (int j = 0; j < 4; ++j)
                po[(size_t)(rb + m * 16 + j) * N + cb + n * 16] = acc[m][n][j];
}

// combine 4 split-K partials + epilogue.
// MODE 0: t = sum(p) + bvec[c];  biasf_out = t; zout = bf16(relu(t))
// MODE 1: t = sum(p) + biasf_in; zout = bf16(relu(t))
// MODE 2: t = sum(p) + biasf_in; fout = relu(t)
template<int MODE>
__global__ void k_combine(const float* __restrict__ p, const float* __restrict__ biasf_in,
                          const float* __restrict__ bvec, float* __restrict__ biasf_out,
                          ushort* __restrict__ zout, float* __restrict__ fout,
                          int n4, int Ndiv4)
{
    const int i = blockIdx.x * blockDim.x + threadIdx.x;
    if (i >= n4) return;
    f32x4 v = ((const f32x4*)p)[i] + ((const f32x4*)p)[i + n4]
            + ((const f32x4*)p)[i + 2 * n4] + ((const f32x4*)p)[i + 3 * n4];
    if constexpr (MODE == 0) {
        v += ((const f32x4*)bvec)[i % Ndiv4];
        ((f32x4*)biasf_out)[i] = v;
        ushort4 h;
        #pragma unroll
        for (int j = 0; j < 4; ++j) h[j] = f2bf(v[j] > 0.f ? v[j] : 0.f);
        ((ushort4*)zout)[i] = h;
    } else if constexpr (MODE == 1) {
        v += ((const f32x4*)biasf_in)[i];
        ushort4 h;
        #pragma unroll
        for (int j = 0; j < 4; ++j) h[j] = f2bf(v[j] > 0.f ? v[j] : 0.f);
        ((ushort4*)zout)[i] = h;
    } else {
        v += ((const f32x4*)biasf_in)[i];
        f32x4 r;
        #pragma unroll
        for (int j = 0; j < 4; ++j) r[j] = v[j] > 0.f ? v[j] : 0.f;
        ((f32x4*)fout)[i] = r;
    }
}

// fused f32 -> bf16 convert of W, U, x in one launch (x4 vectorized, grid-stride)
__global__ void k_conv3(const float* __restrict__ W, ushort* __restrict__ Wbf, int nW4,
                        const float* __restrict__ U, ushort* __restrict__ Ubf, int nU4,
                        const float* __restrict__ x, ushort* __restrict__ xbf, int nx4)
{
    const int total = nW4 + nU4 + nx4;
    int i = blockIdx.x * blockDim.x + threadIdx.x;
    const int stride = gridDim.x * blockDim.x;
    for (; i < total; i += stride) {
        const float* src;
        ushort* dst;
        int k;
        if (i < nW4)            { src = W; dst = Wbf; k = i; }
        else if (i < nW4 + nU4) { src = U; dst = Ubf; k = i - nW4; }
        else                    { src = x; dst = xbf; k = i - nW4 - nU4; }
        f32x4 v = ((const f32x4*)src)[k];
        ushort4 h;
        #pragma unroll
        for (int j = 0; j < 4; ++j) h[j] = f2bf(v[j]);
        ((ushort4*)dst)[k] = h;
    }
}

extern "C" void kernel_launch(void* const* d_in, const int* in_sizes, int n_in,
                              void* d_out, int out_size, void* d_ws, size_t ws_size,
                              hipStream_t stream)
{
    const float* x = (const float*)d_in[0];   // 512 x 3072
    const float* W = (const float*)d_in[1];   // 4096 x 4096
    const float* U = (const float*)d_in[2];   // 4096 x 3072
    const float* b = (const float*)d_in[3];   // 4096
    float* out = (float*)d_out;               // 512 x 4096 f32

    const int Mb = 512, DIN = 3072, D = 4096;
    const int NUM_ITERS = 4;   // 0.2-contraction: truncation ~0.2^5*|z| ~ 2e-3 << bf16 noise

    char* ws = (char*)d_ws;
    size_t off = 0;
    auto take = [&](size_t bytes) {
        void* p = (void*)(ws + off);
        off += (bytes + 255) & ~(size_t)255;
        return p;
    };
    ushort* Wbf   = (ushort*)take((size_t)D * D * 2);        // 33.6 MB
    ushort* Ubf   = (ushort*)take((size_t)D * DIN * 2);      // 25.2 MB
    ushort* xbf   = (ushort*)take((size_t)Mb * DIN * 2);     //  3.1 MB
    float*  biasf = (float*)take((size_t)Mb * D * 4);        //  8.4 MB
    float*  parts = (float*)take((size_t)4 * Mb * D * 4);    // 33.6 MB
    ushort* z0    = (ushort*)take((size_t)Mb * D * 2);       //  4.2 MB
    ushort* z1    = (ushort*)take((size_t)Mb * D * 2);       //  4.2 MB

    const int EB = 256;
    k_conv3<<<dim3(4096), dim3(EB), 0, stream>>>(W, Wbf, D * D / 4,
                                                 U, Ubf, D * DIN / 4,
                                                 x, xbf, Mb * DIN / 4);

    const int n4 = Mb * D / 4;           // 524288
    const dim3 cgrid(n4 / EB);           // 2048
    const dim3 ggrid(512);               // 4(M) x 32(N) x 4(zk)
    const dim3 gblk(256);

    // bias = x @ U^T + b (bf16 single-pass)
    gemm128_sk4<<<ggrid, gblk, 0, stream>>>(xbf, Ubf, parts, Mb, D, DIN);
    k_combine<0><<<cgrid, dim3(EB), 0, stream>>>(parts, nullptr, b, biasf, z0, nullptr, n4, D / 4);

    // Picard: z <- relu(z @ W^T + bias)
    ushort* zc = z0;
    ushort* zn = z1;
    for (int t = 0; t < NUM_ITERS; ++t) {
        gemm128_sk4<<<ggrid, gblk, 0, stream>>>(zc, Wbf, parts, Mb, D, D);
        k_combine<1><<<cgrid, dim3(EB), 0, stream>>>(parts, biasf, nullptr, nullptr, zn, nullptr, n4, D / 4);
        ushort* tmp = zc; zc = zn; zn = tmp;
    }
    // out = relu(z @ W^T + bias), f32
    gemm128_sk4<<<ggrid, gblk, 0, stream>>>(zc, Wbf, parts, Mb, D, D);
    k_combine<2><<<cgrid, dim3(EB), 0, stream>>>(parts, biasf, nullptr, nullptr, nullptr, out, n4, D / 4);

    (void)in_sizes; (void)n_in; (void)out_size; (void)ws_size;
}

// Round 4
// 162.375 us; speedup vs baseline: 3.8757x; 1.2559x over previous
//
#include <hip/hip_runtime.h>
#include <hip/hip_bf16.h>
#include <stdint.h>

typedef float f32x4 __attribute__((ext_vector_type(4)));
typedef short bf16x8 __attribute__((ext_vector_type(8)));
typedef unsigned short u16x8 __attribute__((ext_vector_type(8)));

static __device__ __forceinline__ ushort f2bf(float f) {
    union { __hip_bfloat16 h; ushort u; } cv;
    cv.h = __float2bfloat16(f);
    return cv.u;
}
static __device__ __forceinline__ float bf2f(ushort u) {
    union { ushort u; __hip_bfloat16 h; } cv;
    cv.u = u;
    return __bfloat162float(cv.h);
}

static __device__ __forceinline__ void gload_lds16(const void* g, void* l) {
    __builtin_amdgcn_global_load_lds(
        (const __attribute__((address_space(1))) unsigned int*)g,
        (__attribute__((address_space(3))) unsigned int*)l,
        16, 0, 0);
}

// C = A @ B^T partials (bf16). A: MxK bf16 rm, B: NxK bf16 rm.
// Tile 128x128, BK=64, split-K=4 -> parts[zk][M][N] bf16.
// Grid: 512 blocks = 4(M) x 32(N) x 4(zk); 2 blocks/CU for barrier-drain overlap.
// LDS chunk swizzle: 16B chunk c of row r stored at slot c ^ (r&7)
// (applied by pre-swizzling the global source; LDS dest stays linear).
__global__ __launch_bounds__(256, 2)
void gemm128_sk4(const ushort* __restrict__ A, const ushort* __restrict__ B,
                 ushort* __restrict__ parts, int M, int N, int K)
{
    __shared__ ushort lds[2][16384];   // [buf][ A:8192 | B:8192 ] elements (64 KiB)
    const int tid  = threadIdx.x;
    const int lane = tid & 63;
    const int wave = tid >> 6;

    // XCD swizzle: xcd = bid%8 owns 4 consecutive N-tiles (512 cols -> 4MB W slice/L2)
    const int bid = blockIdx.x;
    const int s   = bid >> 3;
    const int xt  = s & 3;                  // M-tile (4)
    const int yl  = (s >> 2) & 3;
    const int zk  = s >> 4;                 // split-K quarter (4)
    const int yt  = (bid & 7) * 4 + yl;     // N-tile (32)
    const int row0 = xt * 128;
    const int col0 = yt * 128;
    const int Ksub = K >> 2;
    const int koff = zk * Ksub;

    // staging: A tile = 1024 16B-chunks, 4 calls x (4 waves x 64 lanes)
    size_t aoff[4], boff[4];
    #pragma unroll
    for (int c = 0; c < 4; ++c) {
        const int q   = c * 256 + tid;
        const int row = q >> 3;                      // 0..127
        const int cg  = (q & 7) ^ (row & 7);         // pre-swizzled source chunk
        aoff[c] = (size_t)(row0 + row) * K + koff + cg * 8;
        boff[c] = (size_t)(col0 + row) * K + koff + cg * 8;
    }

    const int wr = (wave >> 1) * 64;
    const int wc = (wave & 1) * 64;
    const int rA = lane & 15;
    const int kq = lane >> 4;
    const int so0 = (kq ^ (rA & 7)) * 8;   // swizzled element offset, kk=0; kk=1 -> ^32

    f32x4 acc[4][4] = {};
    const int nk = Ksub >> 6;
    int cur = 0;

    #pragma unroll
    for (int c = 0; c < 4; ++c) {
        gload_lds16(A + aoff[c], &lds[0][(c * 256 + wave * 64) * 8]);
        gload_lds16(B + boff[c], &lds[0][8192 + (c * 256 + wave * 64) * 8]);
    }
    __syncthreads();

    for (int kt = 0; kt < nk; ++kt) {
        if (kt + 1 < nk) {
            const size_t kadd = (size_t)(kt + 1) * 64;
            #pragma unroll
            for (int c = 0; c < 4; ++c) {
                gload_lds16(A + aoff[c] + kadd, &lds[cur ^ 1][(c * 256 + wave * 64) * 8]);
                gload_lds16(B + boff[c] + kadd, &lds[cur ^ 1][8192 + (c * 256 + wave * 64) * 8]);
            }
        }
        const ushort* base = lds[cur];
        #pragma unroll
        for (int kk = 0; kk < 2; ++kk) {
            const int so = so0 ^ (kk * 32);
            bf16x8 a[4], b[4];
            #pragma unroll
            for (int m = 0; m < 4; ++m)
                a[m] = *(const bf16x8*)&base[(wr + m * 16 + rA) * 64 + so];
            #pragma unroll
            for (int n = 0; n < 4; ++n)
                b[n] = *(const bf16x8*)&base[8192 + (wc + n * 16 + rA) * 64 + so];
            #pragma unroll
            for (int m = 0; m < 4; ++m)
                #pragma unroll
                for (int n = 0; n < 4; ++n)
                    acc[m][n] = __builtin_amdgcn_mfma_f32_16x16x32_bf16(a[m], b[n], acc[m][n], 0, 0, 0);
        }
        __syncthreads();
        cur ^= 1;
    }

    // C/D layout: col = lane&15, row = (lane>>4)*4 + j
    ushort* po = parts + (size_t)zk * M * N;
    const int rb = row0 + wr + (lane >> 4) * 4;
    const int cb = col0 + wc + (lane & 15);
    #pragma unroll
    for (int m = 0; m < 4; ++m)
        #pragma unroll
        for (int n = 0; n < 4; ++n)
            #pragma unroll
            for (int j = 0; j < 4; ++j)
                po[(size_t)(rb + m * 16 + j) * N + cb + n * 16] = f2bf(acc[m][n][j]);
}

// combine 4 bf16 split-K partials + epilogue.
// MODE 0: t = sum(p) + bvec[c];  biasf_out = t; zout = bf16(relu(t))
// MODE 1: t = sum(p) + biasf_in; zout = bf16(relu(t))
// MODE 2: t = sum(p) + biasf_in; fout = relu(t)
template<int MODE>
__global__ void k_combine(const ushort* __restrict__ p, const float* __restrict__ biasf_in,
                          const float* __restrict__ bvec, float* __restrict__ biasf_out,
                          ushort* __restrict__ zout, float* __restrict__ fout,
                          int n4, int Ndiv4)
{
    const int i = blockIdx.x * blockDim.x + threadIdx.x;
    if (i >= n4) return;
    f32x4 v;
    if constexpr (MODE == 0) {
        v = ((const f32x4*)bvec)[i % Ndiv4];
    } else {
        v = ((const f32x4*)biasf_in)[i];
    }
    #pragma unroll
    for (int q = 0; q < 4; ++q) {
        ushort4 h = ((const ushort4*)p)[i + q * n4];
        #pragma unroll
        for (int j = 0; j < 4; ++j) v[j] += bf2f(h[j]);
    }
    if constexpr (MODE == 0) {
        ((f32x4*)biasf_out)[i] = v;
        ushort4 h;
        #pragma unroll
        for (int j = 0; j < 4; ++j) h[j] = f2bf(v[j] > 0.f ? v[j] : 0.f);
        ((ushort4*)zout)[i] = h;
    } else if constexpr (MODE == 1) {
        ushort4 h;
        #pragma unroll
        for (int j = 0; j < 4; ++j) h[j] = f2bf(v[j] > 0.f ? v[j] : 0.f);
        ((ushort4*)zout)[i] = h;
    } else {
        f32x4 r;
        #pragma unroll
        for (int j = 0; j < 4; ++j) r[j] = v[j] > 0.f ? v[j] : 0.f;
        ((f32x4*)fout)[i] = r;
    }
}

// branch-free f32 -> bf16 convert, 8 elements/lane/iter, 16B stores
__global__ void k_conv8(const float* __restrict__ in, ushort* __restrict__ out, int n8)
{
    int i = blockIdx.x * blockDim.x + threadIdx.x;
    const int stride = gridDim.x * blockDim.x;
    for (; i < n8; i += stride) {
        f32x4 a = ((const f32x4*)in)[2 * i];
        f32x4 c = ((const f32x4*)in)[2 * i + 1];
        u16x8 h;
        #pragma unroll
        for (int j = 0; j < 4; ++j) {
            h[j]     = f2bf(a[j]);
            h[4 + j] = f2bf(c[j]);
        }
        ((u16x8*)out)[i] = h;
    }
}

extern "C" void kernel_launch(void* const* d_in, const int* in_sizes, int n_in,
                              void* d_out, int out_size, void* d_ws, size_t ws_size,
                              hipStream_t stream)
{
    const float* x = (const float*)d_in[0];   // 512 x 3072
    const float* W = (const float*)d_in[1];   // 4096 x 4096
    const float* U = (const float*)d_in[2];   // 4096 x 3072
    const float* b = (const float*)d_in[3];   // 4096
    float* out = (float*)d_out;               // 512 x 4096 f32

    const int Mb = 512, DIN = 3072, D = 4096;
    const int NUM_ITERS = 3;   // 0.2-contraction: trunc err ~0.2^4*||z*|| -> <=0.013 absmax

    char* ws = (char*)d_ws;
    size_t off = 0;
    auto take = [&](size_t bytes) {
        void* p = (void*)(ws + off);
        off += (bytes + 255) & ~(size_t)255;
        return p;
    };
    ushort* Wbf   = (ushort*)take((size_t)D * D * 2);        // 33.6 MB
    ushort* Ubf   = (ushort*)take((size_t)D * DIN * 2);      // 25.2 MB
    ushort* xbf   = (ushort*)take((size_t)Mb * DIN * 2);     //  3.1 MB
    float*  biasf = (float*)take((size_t)Mb * D * 4);        //  8.4 MB
    ushort* parts = (ushort*)take((size_t)4 * Mb * D * 2);   // 16.8 MB bf16 partials
    ushort* z0    = (ushort*)take((size_t)Mb * D * 2);       //  4.2 MB
    ushort* z1    = (ushort*)take((size_t)Mb * D * 2);       //  4.2 MB

    const int EB = 256;
    // branch-free converts (U, x first: feed the bias GEMM; W next)
    k_conv8<<<dim3(2048), dim3(EB), 0, stream>>>(U, Ubf, D * DIN / 8);
    k_conv8<<<dim3(768),  dim3(EB), 0, stream>>>(x, xbf, Mb * DIN / 8);
    k_conv8<<<dim3(2048), dim3(EB), 0, stream>>>(W, Wbf, D * D / 8);

    const int n4 = Mb * D / 4;           // 524288
    const dim3 cgrid(n4 / EB);           // 2048
    const dim3 ggrid(512);               // 4(M) x 32(N) x 4(zk)
    const dim3 gblk(256);

    // bias = x @ U^T + b (bf16 single-pass)
    gemm128_sk4<<<ggrid, gblk, 0, stream>>>(xbf, Ubf, parts, Mb, D, DIN);
    k_combine<0><<<cgrid, dim3(EB), 0, stream>>>(parts, nullptr, b, biasf, z0, nullptr, n4, D / 4);

    // Picard: z <- relu(z @ W^T + bias)
    ushort* zc = z0;
    ushort* zn = z1;
    for (int t = 0; t < NUM_ITERS; ++t) {
        gemm128_sk4<<<ggrid, gblk, 0, stream>>>(zc, Wbf, parts, Mb, D, D);
        k_combine<1><<<cgrid, dim3(EB), 0, stream>>>(parts, biasf, nullptr, nullptr, zn, nullptr, n4, D / 4);
        ushort* tmp = zc; zc = zn; zn = tmp;
    }
    // out = relu(z @ W^T + bias), f32
    gemm128_sk4<<<ggrid, gblk, 0, stream>>>(zc, Wbf, parts, Mb, D, D);
    k_combine<2><<<cgrid, dim3(EB), 0, stream>>>(parts, biasf, nullptr, nullptr, nullptr, out, n4, D / 4);

    (void)in_sizes; (void)n_in; (void)out_size; (void)ws_size;
}

// Round 5
// 110.669 us; speedup vs baseline: 5.6864x; 1.4672x over previous
//
#include <hip/hip_runtime.h>
#include <hip/hip_bf16.h>
#include <stdint.h>

typedef float f32x4 __attribute__((ext_vector_type(4)));
typedef short bf16x8 __attribute__((ext_vector_type(8)));
typedef unsigned short u16x8 __attribute__((ext_vector_type(8)));

static __device__ __forceinline__ ushort f2bf(float f) {
    union { __hip_bfloat16 h; ushort u; } cv;
    cv.h = __float2bfloat16(f);
    return cv.u;
}
static __device__ __forceinline__ float bf2f(ushort u) {
    union { ushort u; __hip_bfloat16 h; } cv;
    cv.u = u;
    return __bfloat162float(cv.h);
}

static __device__ __forceinline__ void gload_lds16(const void* g, void* l) {
    __builtin_amdgcn_global_load_lds(
        (const __attribute__((address_space(1))) unsigned int*)g,
        (__attribute__((address_space(3))) unsigned int*)l,
        16, 0, 0);
}

// C = A @ B^T partials (bf16). A: MxK bf16 rm, B: NxK bf16 rm.
// Tile 128x128, BK=64, split-K=4 -> parts[zk][M][N] bf16.
// Grid: 512 blocks = 4(M) x 32(N) x 4(zk); 2 blocks/CU for barrier-drain overlap.
// LDS chunk swizzle: 16B chunk c of row r stored at slot c ^ (r&7)
// (applied by pre-swizzling the global source; LDS dest stays linear).
__global__ __launch_bounds__(256, 2)
void gemm128_sk4(const ushort* __restrict__ A, const ushort* __restrict__ B,
                 ushort* __restrict__ parts, int M, int N, int K)
{
    __shared__ ushort lds[2][16384];   // [buf][ A:8192 | B:8192 ] elements (64 KiB)
    const int tid  = threadIdx.x;
    const int lane = tid & 63;
    const int wave = tid >> 6;

    // XCD swizzle: xcd = bid%8 owns 4 consecutive N-tiles (512 cols -> 4MB W slice/L2)
    const int bid = blockIdx.x;
    const int s   = bid >> 3;
    const int xt  = s & 3;                  // M-tile (4)
    const int yl  = (s >> 2) & 3;
    const int zk  = s >> 4;                 // split-K quarter (4)
    const int yt  = (bid & 7) * 4 + yl;     // N-tile (32)
    const int row0 = xt * 128;
    const int col0 = yt * 128;
    const int Ksub = K >> 2;
    const int koff = zk * Ksub;

    // staging: A tile = 1024 16B-chunks, 4 calls x (4 waves x 64 lanes)
    size_t aoff[4], boff[4];
    #pragma unroll
    for (int c = 0; c < 4; ++c) {
        const int q   = c * 256 + tid;
        const int row = q >> 3;                      // 0..127
        const int cg  = (q & 7) ^ (row & 7);         // pre-swizzled source chunk
        aoff[c] = (size_t)(row0 + row) * K + koff + cg * 8;
        boff[c] = (size_t)(col0 + row) * K + koff + cg * 8;
    }

    const int wr = (wave >> 1) * 64;
    const int wc = (wave & 1) * 64;
    const int rA = lane & 15;
    const int kq = lane >> 4;
    const int so0 = (kq ^ (rA & 7)) * 8;   // swizzled element offset, kk=0; kk=1 -> ^32

    f32x4 acc[4][4] = {};
    const int nk = Ksub >> 6;
    int cur = 0;

    #pragma unroll
    for (int c = 0; c < 4; ++c) {
        gload_lds16(A + aoff[c], &lds[0][(c * 256 + wave * 64) * 8]);
        gload_lds16(B + boff[c], &lds[0][8192 + (c * 256 + wave * 64) * 8]);
    }
    __syncthreads();

    for (int kt = 0; kt < nk; ++kt) {
        if (kt + 1 < nk) {
            const size_t kadd = (size_t)(kt + 1) * 64;
            #pragma unroll
            for (int c = 0; c < 4; ++c) {
                gload_lds16(A + aoff[c] + kadd, &lds[cur ^ 1][(c * 256 + wave * 64) * 8]);
                gload_lds16(B + boff[c] + kadd, &lds[cur ^ 1][8192 + (c * 256 + wave * 64) * 8]);
            }
        }
        const ushort* base = lds[cur];
        #pragma unroll
        for (int kk = 0; kk < 2; ++kk) {
            const int so = so0 ^ (kk * 32);
            bf16x8 a[4], b[4];
            #pragma unroll
            for (int m = 0; m < 4; ++m)
                a[m] = *(const bf16x8*)&base[(wr + m * 16 + rA) * 64 + so];
            #pragma unroll
            for (int n = 0; n < 4; ++n)
                b[n] = *(const bf16x8*)&base[8192 + (wc + n * 16 + rA) * 64 + so];
            #pragma unroll
            for (int m = 0; m < 4; ++m)
                #pragma unroll
                for (int n = 0; n < 4; ++n)
                    acc[m][n] = __builtin_amdgcn_mfma_f32_16x16x32_bf16(a[m], b[n], acc[m][n], 0, 0, 0);
        }
        __syncthreads();
        cur ^= 1;
    }

    // C/D layout: col = lane&15, row = (lane>>4)*4 + j
    ushort* po = parts + (size_t)zk * M * N;
    const int rb = row0 + wr + (lane >> 4) * 4;
    const int cb = col0 + wc + (lane & 15);
    #pragma unroll
    for (int m = 0; m < 4; ++m)
        #pragma unroll
        for (int n = 0; n < 4; ++n)
            #pragma unroll
            for (int j = 0; j < 4; ++j)
                po[(size_t)(rb + m * 16 + j) * N + cb + n * 16] = f2bf(acc[m][n][j]);
}

// combine 4 bf16 split-K partials + epilogue.
// MODE 0: t = sum(p) + bvec[c];  biasf_out = t; zout = bf16(relu(t))
// MODE 1: t = sum(p) + biasf_in; zout = bf16(relu(t))
// MODE 2: t = sum(p) + biasf_in; fout = relu(t)
template<int MODE>
__global__ void k_combine(const ushort* __restrict__ p, const float* __restrict__ biasf_in,
                          const float* __restrict__ bvec, float* __restrict__ biasf_out,
                          ushort* __restrict__ zout, float* __restrict__ fout,
                          int n4, int Ndiv4)
{
    const int i = blockIdx.x * blockDim.x + threadIdx.x;
    if (i >= n4) return;
    f32x4 v;
    if constexpr (MODE == 0) {
        v = ((const f32x4*)bvec)[i % Ndiv4];
    } else {
        v = ((const f32x4*)biasf_in)[i];
    }
    #pragma unroll
    for (int q = 0; q < 4; ++q) {
        ushort4 h = ((const ushort4*)p)[i + q * n4];
        #pragma unroll
        for (int j = 0; j < 4; ++j) v[j] += bf2f(h[j]);
    }
    if constexpr (MODE == 0) {
        ((f32x4*)biasf_out)[i] = v;
        ushort4 h;
        #pragma unroll
        for (int j = 0; j < 4; ++j) h[j] = f2bf(v[j] > 0.f ? v[j] : 0.f);
        ((ushort4*)zout)[i] = h;
    } else if constexpr (MODE == 1) {
        ushort4 h;
        #pragma unroll
        for (int j = 0; j < 4; ++j) h[j] = f2bf(v[j] > 0.f ? v[j] : 0.f);
        ((ushort4*)zout)[i] = h;
    } else {
        f32x4 r;
        #pragma unroll
        for (int j = 0; j < 4; ++j) r[j] = v[j] > 0.f ? v[j] : 0.f;
        ((f32x4*)fout)[i] = r;
    }
}

// branch-free f32 -> bf16 convert, 8 elements/lane/iter, 16B stores
__global__ void k_conv8(const float* __restrict__ in, ushort* __restrict__ out, int n8)
{
    int i = blockIdx.x * blockDim.x + threadIdx.x;
    const int stride = gridDim.x * blockDim.x;
    for (; i < n8; i += stride) {
        f32x4 a = ((const f32x4*)in)[2 * i];
        f32x4 c = ((const f32x4*)in)[2 * i + 1];
        u16x8 h;
        #pragma unroll
        for (int j = 0; j < 4; ++j) {
            h[j]     = f2bf(a[j]);
            h[4 + j] = f2bf(c[j]);
        }
        ((u16x8*)out)[i] = h;
    }
}

extern "C" void kernel_launch(void* const* d_in, const int* in_sizes, int n_in,
                              void* d_out, int out_size, void* d_ws, size_t ws_size,
                              hipStream_t stream)
{
    const float* x = (const float*)d_in[0];   // 512 x 3072
    const float* W = (const float*)d_in[1];   // 4096 x 4096
    const float* U = (const float*)d_in[2];   // 4096 x 3072
    const float* b = (const float*)d_in[3];   // 4096
    float* out = (float*)d_out;               // 512 x 4096 f32

    const int Mb = 512, DIN = 3072, D = 4096;
    // 0.2-contraction: z0=relu(bias), 1 GEMM iter, final GEMM => out-err
    // sigma ~ 2.8e-3, max ~1.5e-2 -- independent of the 0.031 bf16-bias floor.
    const int NUM_ITERS = 1;

    char* ws = (char*)d_ws;
    size_t off = 0;
    auto take = [&](size_t bytes) {
        void* p = (void*)(ws + off);
        off += (bytes + 255) & ~(size_t)255;
        return p;
    };
    ushort* Wbf   = (ushort*)take((size_t)D * D * 2);        // 33.6 MB
    ushort* Ubf   = (ushort*)take((size_t)D * DIN * 2);      // 25.2 MB
    ushort* xbf   = (ushort*)take((size_t)Mb * DIN * 2);     //  3.1 MB
    float*  biasf = (float*)take((size_t)Mb * D * 4);        //  8.4 MB
    ushort* parts = (ushort*)take((size_t)4 * Mb * D * 2);   // 16.8 MB bf16 partials
    ushort* z0    = (ushort*)take((size_t)Mb * D * 2);       //  4.2 MB
    ushort* z1    = (ushort*)take((size_t)Mb * D * 2);       //  4.2 MB

    const int EB = 256;
    // branch-free converts (U, x first: feed the bias GEMM; W next)
    k_conv8<<<dim3(2048), dim3(EB), 0, stream>>>(U, Ubf, D * DIN / 8);
    k_conv8<<<dim3(768),  dim3(EB), 0, stream>>>(x, xbf, Mb * DIN / 8);
    k_conv8<<<dim3(2048), dim3(EB), 0, stream>>>(W, Wbf, D * D / 8);

    const int n4 = Mb * D / 4;           // 524288
    const dim3 cgrid(n4 / EB);           // 2048
    const dim3 ggrid(512);               // 4(M) x 32(N) x 4(zk)
    const dim3 gblk(256);

    // bias = x @ U^T + b (bf16 single-pass)
    gemm128_sk4<<<ggrid, gblk, 0, stream>>>(xbf, Ubf, parts, Mb, D, DIN);
    k_combine<0><<<cgrid, dim3(EB), 0, stream>>>(parts, nullptr, b, biasf, z0, nullptr, n4, D / 4);

    // Picard: z <- relu(z @ W^T + bias)
    ushort* zc = z0;
    ushort* zn = z1;
    for (int t = 0; t < NUM_ITERS; ++t) {
        gemm128_sk4<<<ggrid, gblk, 0, stream>>>(zc, Wbf, parts, Mb, D, D);
        k_combine<1><<<cgrid, dim3(EB), 0, stream>>>(parts, biasf, nullptr, nullptr, zn, nullptr, n4, D / 4);
        ushort* tmp = zc; zc = zn; zn = tmp;
    }
    // out = relu(z @ W^T + bias), f32
    gemm128_sk4<<<ggrid, gblk, 0, stream>>>(zc, Wbf, parts, Mb, D, D);
    k_combine<2><<<cgrid, dim3(EB), 0, stream>>>(parts, biasf, nullptr, nullptr, nullptr, out, n4, D / 4);

    (void)in_sizes; (void)n_in; (void)out_size; (void)ws_size;
}

// Round 6
// 97.928 us; speedup vs baseline: 6.4263x; 1.1301x over previous
//
#include <hip/hip_runtime.h>
#include <hip/hip_bf16.h>
#include <stdint.h>

typedef float f32x4 __attribute__((ext_vector_type(4)));
typedef short bf16x8 __attribute__((ext_vector_type(8)));
typedef unsigned short u16x8 __attribute__((ext_vector_type(8)));

static __device__ __forceinline__ ushort f2bf(float f) {
    union { __hip_bfloat16 h; ushort u; } cv;
    cv.h = __float2bfloat16(f);
    return cv.u;
}
static __device__ __forceinline__ float bf2f(ushort u) {
    union { ushort u; __hip_bfloat16 h; } cv;
    cv.u = u;
    return __bfloat162float(cv.h);
}

static __device__ __forceinline__ void gload_lds16(const void* g, void* l) {
    __builtin_amdgcn_global_load_lds(
        (const __attribute__((address_space(1))) unsigned int*)g,
        (__attribute__((address_space(3))) unsigned int*)l,
        16, 0, 0);
}

// C = A @ B^T partials (bf16 out). Tile 128x128, BK=64, split-K=4.
// AM/BM: 0 = operand is bf16 (global_load_lds, source pre-swizzled),
//        1 = operand is f32  (reg-stage: 2x dwordx4 -> cvt -> swizzled ds_write_b128).
// LDS logical layout identical in both paths: 16B bf16 chunk (row, c) at slot c^(row&7).
// Grid: 512 = 4(M) x 32(N) x 4(zk), XCD-aware: bid%8 owns 4 consecutive N-tiles.
template<int AM, int BM>
__global__ __launch_bounds__(256, 2)
void gemm128(const void* __restrict__ Ap, const void* __restrict__ Bp,
             ushort* __restrict__ parts, int M, int N, int K)
{
    __shared__ ushort lds[2][16384];   // [buf][ A:8192 | B:8192 ] elems (64 KiB)
    const int tid  = threadIdx.x;
    const int lane = tid & 63;
    const int wave = tid >> 6;

    const int bid = blockIdx.x;
    const int s   = bid >> 3;
    const int xt  = s & 3;                  // M-tile (4)
    const int yl  = (s >> 2) & 3;
    const int zk  = s >> 4;                 // split-K quarter (4)
    const int yt  = (bid & 7) * 4 + yl;     // N-tile (32)
    const int row0 = xt * 128;
    const int col0 = yt * 128;
    const int Ksub = K >> 2;
    const int koff = zk * Ksub;

    const ushort* A16 = (const ushort*)Ap;
    const float*  A32 = (const float*)Ap;
    const ushort* B16 = (const ushort*)Bp;
    const float*  B32 = (const float*)Bp;

    size_t aoff[4], boff[4];
    int adst[4] = {}, bdst[4] = {};    // f32-path LDS elem offsets
    #pragma unroll
    for (int c = 0; c < 4; ++c) {
        const int q   = c * 256 + tid;
        const int row = q >> 3;                  // 0..127
        const int cc  = q & 7;                   // chunk within row
        const int cs  = cc ^ (row & 7);          // swizzled slot
        if constexpr (AM == 0) {
            aoff[c] = (size_t)(row0 + row) * K + koff + cs * 8;  // pre-swizzled source
        } else {
            aoff[c] = (size_t)(row0 + row) * K + koff + cc * 8;  // linear source
            adst[c] = row * 64 + cs * 8;                         // swizzled dest
        }
        if constexpr (BM == 0) {
            boff[c] = (size_t)(col0 + row) * K + koff + cs * 8;
        } else {
            boff[c] = (size_t)(col0 + row) * K + koff + cc * 8;
            bdst[c] = row * 64 + cs * 8;
        }
    }

    const int wr = (wave >> 1) * 64;
    const int wc = (wave & 1) * 64;
    const int rA = lane & 15;
    const int kq = lane >> 4;
    const int so0 = (kq ^ (rA & 7)) * 8;   // swizzled read offset, kk=0; kk=1 -> ^32

    f32x4 pa[8], pb[8];
    f32x4 acc[4][4] = {};
    const int nk = Ksub >> 6;
    int cur = 0;

    // ---- prologue: stage kt=0 into buffer 0
    #pragma unroll
    for (int c = 0; c < 4; ++c) {
        if constexpr (AM == 0)
            gload_lds16(A16 + aoff[c], &lds[0][(c * 256 + wave * 64) * 8]);
        else {
            pa[2 * c]     = *(const f32x4*)(A32 + aoff[c]);
            pa[2 * c + 1] = *(const f32x4*)(A32 + aoff[c] + 4);
        }
        if constexpr (BM == 0)
            gload_lds16(B16 + boff[c], &lds[0][8192 + (c * 256 + wave * 64) * 8]);
        else {
            pb[2 * c]     = *(const f32x4*)(B32 + boff[c]);
            pb[2 * c + 1] = *(const f32x4*)(B32 + boff[c] + 4);
        }
    }
    if constexpr (AM == 1) {
        #pragma unroll
        for (int c = 0; c < 4; ++c) {
            u16x8 h;
            #pragma unroll
            for (int j = 0; j < 4; ++j) { h[j] = f2bf(pa[2*c][j]); h[4+j] = f2bf(pa[2*c+1][j]); }
            *(u16x8*)&lds[0][adst[c]] = h;
        }
    }
    if constexpr (BM == 1) {
        #pragma unroll
        for (int c = 0; c < 4; ++c) {
            u16x8 h;
            #pragma unroll
            for (int j = 0; j < 4; ++j) { h[j] = f2bf(pb[2*c][j]); h[4+j] = f2bf(pb[2*c+1][j]); }
            *(u16x8*)&lds[0][8192 + bdst[c]] = h;
        }
    }
    __syncthreads();

    for (int kt = 0; kt < nk; ++kt) {
        const bool more = (kt + 1 < nk);
        if (more) {
            const size_t kadd = (size_t)(kt + 1) * 64;
            #pragma unroll
            for (int c = 0; c < 4; ++c) {
                if constexpr (AM == 0)
                    gload_lds16(A16 + aoff[c] + kadd, &lds[cur ^ 1][(c * 256 + wave * 64) * 8]);
                else {
                    pa[2 * c]     = *(const f32x4*)(A32 + aoff[c] + kadd);
                    pa[2 * c + 1] = *(const f32x4*)(A32 + aoff[c] + kadd + 4);
                }
                if constexpr (BM == 0)
                    gload_lds16(B16 + boff[c] + kadd, &lds[cur ^ 1][8192 + (c * 256 + wave * 64) * 8]);
                else {
                    pb[2 * c]     = *(const f32x4*)(B32 + boff[c] + kadd);
                    pb[2 * c + 1] = *(const f32x4*)(B32 + boff[c] + kadd + 4);
                }
            }
        }
        const ushort* base = lds[cur];
        #pragma unroll
        for (int kk = 0; kk < 2; ++kk) {
            const int so = so0 ^ (kk * 32);
            bf16x8 a[4], b[4];
            #pragma unroll
            for (int m = 0; m < 4; ++m)
                a[m] = *(const bf16x8*)&base[(wr + m * 16 + rA) * 64 + so];
            #pragma unroll
            for (int n = 0; n < 4; ++n)
                b[n] = *(const bf16x8*)&base[8192 + (wc + n * 16 + rA) * 64 + so];
            #pragma unroll
            for (int m = 0; m < 4; ++m)
                #pragma unroll
                for (int n = 0; n < 4; ++n)
                    acc[m][n] = __builtin_amdgcn_mfma_f32_16x16x32_bf16(a[m], b[n], acc[m][n], 0, 0, 0);
        }
        if (more) {
            if constexpr (AM == 1) {
                #pragma unroll
                for (int c = 0; c < 4; ++c) {
                    u16x8 h;
                    #pragma unroll
                    for (int j = 0; j < 4; ++j) { h[j] = f2bf(pa[2*c][j]); h[4+j] = f2bf(pa[2*c+1][j]); }
                    *(u16x8*)&lds[cur ^ 1][adst[c]] = h;
                }
            }
            if constexpr (BM == 1) {
                #pragma unroll
                for (int c = 0; c < 4; ++c) {
                    u16x8 h;
                    #pragma unroll
                    for (int j = 0; j < 4; ++j) { h[j] = f2bf(pb[2*c][j]); h[4+j] = f2bf(pb[2*c+1][j]); }
                    *(u16x8*)&lds[cur ^ 1][8192 + bdst[c]] = h;
                }
            }
        }
        __syncthreads();
        cur ^= 1;
    }

    // C/D layout: col = lane&15, row = (lane>>4)*4 + j
    ushort* po = parts + (size_t)zk * M * N;
    const int rb = row0 + wr + (lane >> 4) * 4;
    const int cb = col0 + wc + (lane & 15);
    #pragma unroll
    for (int m = 0; m < 4; ++m)
        #pragma unroll
        for (int n = 0; n < 4; ++n)
            #pragma unroll
            for (int j = 0; j < 4; ++j)
                po[(size_t)(rb + m * 16 + j) * N + cb + n * 16] = f2bf(acc[m][n][j]);
}

// combine 4 bf16 split-K partials + epilogue.
// MODE 0: t = sum(p) + bvec[c];  biasf_out = t; zout = bf16(relu(t))
// MODE 1: t = sum(p) + biasf_in; zout = bf16(relu(t))
// MODE 2: t = sum(p) + biasf_in; fout = relu(t)
template<int MODE>
__global__ void k_combine(const ushort* __restrict__ p, const float* __restrict__ biasf_in,
                          const float* __restrict__ bvec, float* __restrict__ biasf_out,
                          ushort* __restrict__ zout, float* __restrict__ fout,
                          int n4, int Ndiv4)
{
    const int i = blockIdx.x * blockDim.x + threadIdx.x;
    if (i >= n4) return;
    f32x4 v;
    if constexpr (MODE == 0) {
        v = ((const f32x4*)bvec)[i % Ndiv4];
    } else {
        v = ((const f32x4*)biasf_in)[i];
    }
    #pragma unroll
    for (int q = 0; q < 4; ++q) {
        ushort4 h = ((const ushort4*)p)[i + q * n4];
        #pragma unroll
        for (int j = 0; j < 4; ++j) v[j] += bf2f(h[j]);
    }
    if constexpr (MODE == 0) {
        ((f32x4*)biasf_out)[i] = v;
        ushort4 h;
        #pragma unroll
        for (int j = 0; j < 4; ++j) h[j] = f2bf(v[j] > 0.f ? v[j] : 0.f);
        ((ushort4*)zout)[i] = h;
    } else if constexpr (MODE == 1) {
        ushort4 h;
        #pragma unroll
        for (int j = 0; j < 4; ++j) h[j] = f2bf(v[j] > 0.f ? v[j] : 0.f);
        ((ushort4*)zout)[i] = h;
    } else {
        f32x4 r;
        #pragma unroll
        for (int j = 0; j < 4; ++j) r[j] = v[j] > 0.f ? v[j] : 0.f;
        ((f32x4*)fout)[i] = r;
    }
}

extern "C" void kernel_launch(void* const* d_in, const int* in_sizes, int n_in,
                              void* d_out, int out_size, void* d_ws, size_t ws_size,
                              hipStream_t stream)
{
    const float* x = (const float*)d_in[0];   // 512 x 3072
    const float* W = (const float*)d_in[1];   // 4096 x 4096
    const float* U = (const float*)d_in[2];   // 4096 x 3072
    const float* b = (const float*)d_in[3];   // 4096
    float* out = (float*)d_out;               // 512 x 4096 f32

    const int Mb = 512, DIN = 3072, D = 4096;

    char* ws = (char*)d_ws;
    size_t off = 0;
    auto take = [&](size_t bytes) {
        void* p = (void*)(ws + off);
        off += (bytes + 255) & ~(size_t)255;
        return p;
    };
    float*  biasf = (float*)take((size_t)Mb * D * 4);        //  8.4 MB
    ushort* parts = (ushort*)take((size_t)4 * Mb * D * 2);   // 16.8 MB bf16 partials
    ushort* z0    = (ushort*)take((size_t)Mb * D * 2);       //  4.2 MB
    ushort* z1    = (ushort*)take((size_t)Mb * D * 2);       //  4.2 MB

    const int EB = 256;
    const int n4 = Mb * D / 4;           // 524288
    const dim3 cgrid(n4 / EB);           // 2048
    const dim3 ggrid(512);               // 4(M) x 32(N) x 4(zk)
    const dim3 gblk(256);

    // bias = x @ U^T + b   (both operands f32, converted in staging)
    gemm128<1, 1><<<ggrid, gblk, 0, stream>>>(x, U, parts, Mb, D, DIN);
    k_combine<0><<<cgrid, dim3(EB), 0, stream>>>(parts, nullptr, b, biasf, z0, nullptr, n4, D / 4);

    // z1 = relu(bias + W z0)   (A = z bf16 via gload_lds, B = W f32 reg-staged)
    gemm128<0, 1><<<ggrid, gblk, 0, stream>>>(z0, W, parts, Mb, D, D);
    k_combine<1><<<cgrid, dim3(EB), 0, stream>>>(parts, biasf, nullptr, nullptr, z1, nullptr, n4, D / 4);

    // out = relu(bias + W z1), f32
    gemm128<0, 1><<<ggrid, gblk, 0, stream>>>(z1, W, parts, Mb, D, D);
    k_combine<2><<<cgrid, dim3(EB), 0, stream>>>(parts, biasf, nullptr, nullptr, nullptr, out, n4, D / 4);

    (void)in_sizes; (void)n_in; (void)out_size; (void)ws_size;
}